// Round 13
// baseline (47.679 us; speedup 1.0000x reference)
//
#include <hip/hip_runtime.h>
#include <cstdint>
#include <cstddef>

// Problem constants (from reference)
constexpr int B = 8, C = 96, N = 3136, K = 18;
constexpr float C1c = 1e-6f, C2c = 1e-6f;

typedef unsigned int uint32;
typedef unsigned short ushort16;
typedef _Float16 h2 __attribute__((ext_vector_type(2)));

__device__ inline float readlane_f(float v, int l) {
  return __builtin_bit_cast(float,
                            __builtin_amdgcn_readlane(__builtin_bit_cast(int, v), l));
}

// f32 -> f16 (RNE) as raw ushort
__device__ inline ushort16 f2h(float f) {
  return __builtin_bit_cast(ushort16, (_Float16)f);
}
__device__ inline h2 u2h2(uint32 u) { return __builtin_bit_cast(h2, u); }
__device__ inline h2 habs2(h2 v) {
  return __builtin_bit_cast(h2, __builtin_bit_cast(uint32, v) & 0x7FFF7FFFu);
}
__device__ inline float2 h22f2(h2 v) {
  return make_float2((float)v.x, (float)v.y);
}

// ---------------------------------------------------------------------------
// Kernel A (fused): transpose x,xp [B,C,N] -> f16 [B,N,C] AND per-column
// channel sums of x in f32 (cstat = {Σx, Σx²}). XCD-pinned: blockIdx&7 == b.
// ---------------------------------------------------------------------------
__global__ __launch_bounds__(256) void fusedT_kernel(
    const float* __restrict__ x, const float* __restrict__ xp,
    ushort16* __restrict__ xT, ushort16* __restrict__ xpT,
    float2* __restrict__ cstat) {
  __shared__ float t0[C][33];
  __shared__ float t1[C][33];
  __shared__ float red1[8][33];
  __shared__ float red2[8][33];
  const int bid = blockIdx.x;
  const int b = bid & 7;              // XCD pin
  const int n0 = (bid >> 3) * 32;
  const int tx = threadIdx.x & 31;
  const int ty = threadIdx.x >> 5;

  const float* xb = x + (size_t)b * C * N;
  const float* xpb = xp + (size_t)b * C * N;
  float s = 0.f, s2 = 0.f;
#pragma unroll
  for (int st = 0; st < 12; ++st) {
    const int c = st * 8 + ty;
    const float v = xb[(size_t)c * N + n0 + tx];
    const float u = xpb[(size_t)c * N + n0 + tx];
    t0[c][tx] = v;
    t1[c][tx] = u;
    s += v;
    s2 += v * v;
  }
  red1[ty][tx] = s;
  red2[ty][tx] = s2;
  __syncthreads();

  ushort16* xTb = xT + (size_t)b * N * C;
  ushort16* xpTb = xpT + (size_t)b * N * C;
  const int tid = threadIdx.x;
#pragma unroll
  for (int r = 0; r < 12; ++r) {
    const int f = r * 256 + tid;      // f = nl*96 + c, coalesced
    const int nl = f / 96;
    const int c = f - nl * 96;
    xTb[(size_t)(n0 + nl) * C + c] = f2h(t0[c][nl]);
    xpTb[(size_t)(n0 + nl) * C + c] = f2h(t1[c][nl]);
  }
  if (ty == 0) {
    float S = 0.f, S2 = 0.f;
#pragma unroll
    for (int yy = 0; yy < 8; ++yy) {
      S += red1[yy][tx];
      S2 += red2[yy][tx];
    }
    cstat[(size_t)b * N + n0 + tx] = make_float2(S, S2);
  }
}

// ---------------------------------------------------------------------------
// Kernel B: main fused kernel — PERSISTENT blocks, R12 body.
// Grid = 2048 blocks (8 per CU, 256 per XCD); block handles batch b =
// blockIdx&7 (XCD pin) and loops over tiles {bslot, bslot+256, bslot+512}
// (+ one spread extra tile for bslot%16==0 covering the 784 = 3*256+16
// remainder). Residency: 32 waves/CU sustained; launch_bounds(256,8)
// forces VGPR<=64 so 8 waves/SIMD is reachable.
// Per tile (4 centers, 1 wave each):
//   Phase 1: group-parallel dots (lane=8g+w; group g owns k={g,g+8,g+16});
//     3x uint2 f16 loads per column; v_dot2_f32_f16; 3-level in-group
//     butterfly; group-parallel sff.
//   Phase 2: lane l<48 owns channels {2l,2l+1}; one 4B half2 load per
//     column; packed v_pk math, 4 alternating f16 partial accumulators.
//   Output: stage 4x96 results in LDS, block-coalesced store to out[B,C,N].
// ---------------------------------------------------------------------------
__global__ __launch_bounds__(256, 8) void ssim_main_kernel(
    const ushort16* __restrict__ xT, const ushort16* __restrict__ xpT,
    const float2* __restrict__ cstat, const int* __restrict__ eidx,
    float* __restrict__ out) {
  __shared__ float ored[4][100];      // [wave][2*48 results], pad 100
  const int wave = threadIdx.x >> 6;
  const int lane = threadIdx.x & 63;
  const int b = blockIdx.x & 7;       // XCD pin: batch == blockIdx % 8
  const int bslot = blockIdx.x >> 3;  // 0..255 within the batch

  const ushort16* xb = xT + (size_t)b * N * C;
  const uint32* xpb32 = (const uint32*)(xpT + (size_t)b * N * C);
  const float2* cs = cstat + (size_t)b * N;
  const int g = lane >> 3;
  const int w = lane & 7;
  const int l = (lane < 48) ? lane : 47;

#pragma unroll 1
  for (int t = 0; t < 4; ++t) {
    int tile;
    if (t < 3) {
      tile = bslot + t * 256;         // tiles 0..767
    } else {
      if ((bslot & 15) != 0) break;   // extras: 16 blocks spread across CUs
      tile = 768 + (bslot >> 4);      // tiles 768..783
    }
    const int n = tile * 4 + wave;

    // lanes 0..17 -> j_k (edge_index[0]), lanes 18..35 -> i_k (edge_index[1])
    int myidx = 0;
    if (lane < 36) {
      const int s = (lane >= 18) ? 1 : 0;
      const int k = lane - 18 * s;
      myidx = eidx[((size_t)(s * B + b) * N + n) * K + k];
    }

    // ---- Phase 1: 3 group-parallel rounds --------------------------------
    float sffr[3];
#pragma unroll
    for (int r = 0; r < 3; ++r) {
      int k = r * 8 + g;
      if (k > K - 1) k = K - 1;       // r=2, g>=2: redundant k=17 (unused)
      const int cj = __shfl(myidx, k, 64);
      const int ci = __shfl(myidx, 18 + k, 64);
      const uint2* xi = (const uint2*)(xb + (size_t)ci * C + 12 * w);
      const uint2* xj = (const uint2*)(xb + (size_t)cj * C + 12 * w);
      const uint2 a0 = xi[0], a1 = xi[1], a2 = xi[2];
      const uint2 q0 = xj[0], q1 = xj[1], q2 = xj[2];
      const float2 si = cs[ci];
      const float2 sj = cs[cj];

      float p = __builtin_amdgcn_fdot2(u2h2(a0.x), u2h2(q0.x), 0.f, false);
      p = __builtin_amdgcn_fdot2(u2h2(a0.y), u2h2(q0.y), p, false);
      p = __builtin_amdgcn_fdot2(u2h2(a1.x), u2h2(q1.x), p, false);
      p = __builtin_amdgcn_fdot2(u2h2(a1.y), u2h2(q1.y), p, false);
      p = __builtin_amdgcn_fdot2(u2h2(a2.x), u2h2(q2.x), p, false);
      p = __builtin_amdgcn_fdot2(u2h2(a2.y), u2h2(q2.y), p, false);
      p += __shfl_xor(p, 1, 64);      // in-group butterfly (8 lanes)
      p += __shfl_xor(p, 2, 64);
      p += __shfl_xor(p, 4, 64);

      const float mi = si.x * (1.0f / C), mj = sj.x * (1.0f / C);
      const float vi = si.y * (1.0f / C) - mi * mi;
      const float vj = sj.y * (1.0f / C) - mj * mj;
      const float cov = p * (1.0f / C) - mi * mj;
      const float S1 = (2.f * mi * mj + C1c) *
                       __builtin_amdgcn_rcpf(mi * mi + mj * mj + C1c);
      const float S2 =
          (2.f * cov + C2c) * __builtin_amdgcn_rcpf(vi + vj + C2c);
      sffr[r] = 1.f - S1 * S2;
    }

    // ---- Broadcast column indices to wave-uniform SGPRs ------------------
    int jjs[K], jis[K];
#pragma unroll
    for (int k = 0; k < K; ++k) {
      jjs[k] = __builtin_amdgcn_readlane(myidx, k);
      jis[k] = __builtin_amdgcn_readlane(myidx, 18 + k);
    }

    // ---- Phase 2: packed f16 xp accumulation -----------------------------
    h2 accT[4] = {h2{0, 0}, h2{0, 0}, h2{0, 0}, h2{0, 0}};
    h2 accX[4] = {h2{0, 0}, h2{0, 0}, h2{0, 0}, h2{0, 0}};
#pragma unroll
    for (int k = 0; k < K; ++k) {
      const float sf = readlane_f(sffr[k >> 3], (k & 7) * 8);
      const _Float16 sh = (_Float16)sf;
      const h2 sf2 = h2{sh, sh};
      const h2 a = u2h2(xpb32[(size_t)jis[k] * 48 + l]);
      const h2 q = u2h2(xpb32[(size_t)jjs[k] * 48 + l]);
      accT[k & 3] = accT[k & 3] + (a + q);
      accX[k & 3] = habs2(a - q) * sf2 + accX[k & 3];
    }
    const float2 t0 = h22f2(accT[0]), t1 = h22f2(accT[1]);
    const float2 t2 = h22f2(accT[2]), t3 = h22f2(accT[3]);
    const float2 x0 = h22f2(accX[0]), x1 = h22f2(accX[1]);
    const float2 x2 = h22f2(accX[2]), x3 = h22f2(accX[3]);
    const float resx =
        (t0.x + t1.x) + (t2.x + t3.x) + (x0.x + x1.x) + (x2.x + x3.x);
    const float resy =
        (t0.y + t1.y) + (t2.y + t3.y) + (x0.y + x1.y) + (x2.y + x3.y);

    // ---- stage results in LDS, then block-coalesced store ----------------
    if (lane < 48) {
      ored[wave][2 * lane] = resx;
      ored[wave][2 * lane + 1] = resy;
    }
    __syncthreads();
    const int n0 = tile * 4;
    const int tid = threadIdx.x;
    {
      const int ch = tid >> 2, nn = tid & 3;  // ch 0..63
      out[((size_t)b * C + ch) * N + n0 + nn] = ored[nn][ch];
    }
    if (tid < 128) {
      const int t2i = 256 + tid;
      const int ch = t2i >> 2, nn = t2i & 3;  // ch 64..95
      out[((size_t)b * C + ch) * N + n0 + nn] = ored[nn][ch];
    }
    __syncthreads();                   // protect ored reuse next iteration
  }
}

// ---------------------------------------------------------------------------
// Fallback (only used if ws_size is too small): slow but correct (f32).
// ---------------------------------------------------------------------------
__global__ void fallback_kernel(const float* __restrict__ x,
                                const float* __restrict__ xp,
                                const int* __restrict__ e,
                                float* __restrict__ out) {
  const int gn = blockIdx.x * 64 + threadIdx.x;
  if (gn >= B * N) return;
  const int b = gn / N;
  const int n = gn - b * N;
  const float* xb = x + (size_t)b * C * N;
  const float* xpb = xp + (size_t)b * C * N;
  int ii[K], jj[K];
  float sff[K];
#pragma unroll
  for (int k = 0; k < K; ++k) {
    jj[k] = e[((size_t)(0 * B + b) * N + n) * K + k];
    ii[k] = e[((size_t)(1 * B + b) * N + n) * K + k];
    float si = 0, sj = 0, sii = 0, sjj = 0, sij = 0;
    for (int c = 0; c < C; ++c) {
      const float a = xb[(size_t)c * N + ii[k]];
      const float q = xb[(size_t)c * N + jj[k]];
      si += a; sj += q; sii += a * a; sjj += q * q; sij += a * q;
    }
    const float mi = si * (1.f / C), mj = sj * (1.f / C);
    const float vi = sii * (1.f / C) - mi * mi;
    const float vj = sjj * (1.f / C) - mj * mj;
    const float cov = sij * (1.f / C) - mi * mj;
    const float S1 = (2.f * mi * mj + C1c) / (mi * mi + mj * mj + C1c);
    const float S2 = (2.f * cov + C2c) / (vi + vj + C2c);
    sff[k] = 1.f - S1 * S2;
  }
  for (int c = 0; c < C; ++c) {
    float acc = 0.f;
#pragma unroll
    for (int k = 0; k < K; ++k) {
      const float a = xpb[(size_t)c * N + ii[k]];
      const float q = xpb[(size_t)c * N + jj[k]];
      acc += a + q + fabsf(a - q) * sff[k];
    }
    out[((size_t)b * C + c) * N + n] = acc;
  }
}

// ---------------------------------------------------------------------------
extern "C" void kernel_launch(void* const* d_in, const int* in_sizes, int n_in,
                              void* d_out, int out_size, void* d_ws, size_t ws_size,
                              hipStream_t stream) {
  const float* x = (const float*)d_in[0];
  const float* xp = (const float*)d_in[1];
  const int* e = (const int*)d_in[2];
  float* out = (float*)d_out;

  const size_t nBNC = (size_t)B * N * C;
  const size_t nBN = (size_t)B * N;
  const size_t need = 2 * nBNC * sizeof(ushort16) + nBN * sizeof(float2);

  if (ws_size >= need) {
    ushort16* xT = (ushort16*)d_ws;
    ushort16* xpT = xT + nBNC;
    float2* cstat = (float2*)(xpT + nBNC);

    fusedT_kernel<<<8 * (N / 32), 256, 0, stream>>>(x, xp, xT, xpT, cstat);
    ssim_main_kernel<<<2048, 256, 0, stream>>>(xT, xpT, cstat, e, out);
  } else {
    fallback_kernel<<<(B * N + 63) / 64, 64, 0, stream>>>(x, xp, e, out);
  }
}

// Round 14
// 36.328 us; speedup vs baseline: 1.3125x; 1.3125x over previous
//
#include <hip/hip_runtime.h>
#include <cstdint>
#include <cstddef>

// Problem constants (from reference)
constexpr int B = 8, C = 96, N = 3136, K = 18;
constexpr float C1c = 1e-6f, C2c = 1e-6f;

typedef unsigned int uint32;
typedef unsigned short ushort16;
typedef _Float16 h2 __attribute__((ext_vector_type(2)));

__device__ inline float readlane_f(float v, int l) {
  return __builtin_bit_cast(float,
                            __builtin_amdgcn_readlane(__builtin_bit_cast(int, v), l));
}

// f32 -> f16 (RNE) as raw ushort
__device__ inline ushort16 f2h(float f) {
  return __builtin_bit_cast(ushort16, (_Float16)f);
}
__device__ inline h2 u2h2(uint32 u) { return __builtin_bit_cast(h2, u); }
__device__ inline h2 habs2(h2 v) {
  return __builtin_bit_cast(h2, __builtin_bit_cast(uint32, v) & 0x7FFF7FFFu);
}
__device__ inline float2 h22f2(h2 v) {
  return make_float2((float)v.x, (float)v.y);
}

// ---------------------------------------------------------------------------
// Kernel A (fused): transpose x,xp [B,C,N] -> f16 [B,N,C] AND per-column
// channel sums of x in f32 (cstat = {Σx, Σx²}). XCD-pinned: blockIdx&7 == b.
// ---------------------------------------------------------------------------
__global__ __launch_bounds__(256) void fusedT_kernel(
    const float* __restrict__ x, const float* __restrict__ xp,
    ushort16* __restrict__ xT, ushort16* __restrict__ xpT,
    float2* __restrict__ cstat) {
  __shared__ float t0[C][33];
  __shared__ float t1[C][33];
  __shared__ float red1[8][33];
  __shared__ float red2[8][33];
  const int bid = blockIdx.x;
  const int b = bid & 7;              // XCD pin
  const int n0 = (bid >> 3) * 32;
  const int tx = threadIdx.x & 31;
  const int ty = threadIdx.x >> 5;

  const float* xb = x + (size_t)b * C * N;
  const float* xpb = xp + (size_t)b * C * N;
  float s = 0.f, s2 = 0.f;
#pragma unroll
  for (int st = 0; st < 12; ++st) {
    const int c = st * 8 + ty;
    const float v = xb[(size_t)c * N + n0 + tx];
    const float u = xpb[(size_t)c * N + n0 + tx];
    t0[c][tx] = v;
    t1[c][tx] = u;
    s += v;
    s2 += v * v;
  }
  red1[ty][tx] = s;
  red2[ty][tx] = s2;
  __syncthreads();

  ushort16* xTb = xT + (size_t)b * N * C;
  ushort16* xpTb = xpT + (size_t)b * N * C;
  const int tid = threadIdx.x;
#pragma unroll
  for (int r = 0; r < 12; ++r) {
    const int f = r * 256 + tid;      // f = nl*96 + c, coalesced
    const int nl = f / 96;
    const int c = f - nl * 96;
    xTb[(size_t)(n0 + nl) * C + c] = f2h(t0[c][nl]);
    xpTb[(size_t)(n0 + nl) * C + c] = f2h(t1[c][nl]);
  }
  if (ty == 0) {
    float S = 0.f, S2 = 0.f;
#pragma unroll
    for (int yy = 0; yy < 8; ++yy) {
      S += red1[yy][tx];
      S2 += red2[yy][tx];
    }
    cstat[(size_t)b * N + n0 + tx] = make_float2(S, S2);
  }
}

// ---------------------------------------------------------------------------
// Kernel B: main fused kernel, two-phase (R4/R12 structure) + f16 payloads.
// One wave per (b,n); XCD-pinned (blockIdx&7 = b).
//   Phase 1: group-parallel dots — lane = 8g+w; group g owns k={g,g+8,g+16};
//     lane covers channels {12w..12w+11} via 3x uint2 (8B) f16 loads per
//     column; dot via 6x v_dot2_f32_f16; 3-level in-group butterfly;
//     group-parallel sff.
//   Broadcast: 36 column indices + 18 sff values -> SGPRs via readlane.
//   Phase 2: lane l<48 owns channels {2l,2l+1}; each xp column is ONE 4B
//     (half2) load; packed v_pk math with 4 alternating f16 partial
//     accumulators (accuracy), f32 combine at the end.
//   Output: block stages 4x96 results in LDS, writes out[B,C,N] with 4
//     consecutive n per 16B segment (4x fewer store segments).
// ---------------------------------------------------------------------------
__global__ __launch_bounds__(256, 4) void ssim_main_kernel(
    const ushort16* __restrict__ xT, const ushort16* __restrict__ xpT,
    const float2* __restrict__ cstat, const int* __restrict__ eidx,
    float* __restrict__ out) {
  __shared__ float ored[4][100];      // [wave][2*48 results], pad 100
  const int wave = threadIdx.x >> 6;
  const int lane = threadIdx.x & 63;
  const int b = blockIdx.x & 7;       // XCD pin: batch == blockIdx % 8
  const int tile = blockIdx.x >> 3;
  const int n = tile * 4 + wave;

  // lanes 0..17 -> j_k (edge_index[0]), lanes 18..35 -> i_k (edge_index[1])
  int myidx = 0;
  if (lane < 36) {
    const int s = (lane >= 18) ? 1 : 0;
    const int k = lane - 18 * s;
    myidx = eidx[((size_t)(s * B + b) * N + n) * K + k];
  }

  const ushort16* xb = xT + (size_t)b * N * C;
  const float2* cs = cstat + (size_t)b * N;
  const int g = lane >> 3;
  const int w = lane & 7;

  // ---- Phase 1: 3 group-parallel rounds ----------------------------------
  float sffr[3];
#pragma unroll
  for (int r = 0; r < 3; ++r) {
    int k = r * 8 + g;
    if (k > K - 1) k = K - 1;         // r=2, g>=2: redundant k=17 (unused)
    const int cj = __shfl(myidx, k, 64);
    const int ci = __shfl(myidx, 18 + k, 64);
    const uint2* xi = (const uint2*)(xb + (size_t)ci * C + 12 * w);
    const uint2* xj = (const uint2*)(xb + (size_t)cj * C + 12 * w);
    const uint2 a0 = xi[0], a1 = xi[1], a2 = xi[2];
    const uint2 q0 = xj[0], q1 = xj[1], q2 = xj[2];
    const float2 si = cs[ci];
    const float2 sj = cs[cj];

    float p = __builtin_amdgcn_fdot2(u2h2(a0.x), u2h2(q0.x), 0.f, false);
    p = __builtin_amdgcn_fdot2(u2h2(a0.y), u2h2(q0.y), p, false);
    p = __builtin_amdgcn_fdot2(u2h2(a1.x), u2h2(q1.x), p, false);
    p = __builtin_amdgcn_fdot2(u2h2(a1.y), u2h2(q1.y), p, false);
    p = __builtin_amdgcn_fdot2(u2h2(a2.x), u2h2(q2.x), p, false);
    p = __builtin_amdgcn_fdot2(u2h2(a2.y), u2h2(q2.y), p, false);
    p += __shfl_xor(p, 1, 64);        // in-group butterfly (8 lanes)
    p += __shfl_xor(p, 2, 64);
    p += __shfl_xor(p, 4, 64);

    const float mi = si.x * (1.0f / C), mj = sj.x * (1.0f / C);
    const float vi = si.y * (1.0f / C) - mi * mi;
    const float vj = sj.y * (1.0f / C) - mj * mj;
    const float cov = p * (1.0f / C) - mi * mj;
    const float S1 =
        (2.f * mi * mj + C1c) * __builtin_amdgcn_rcpf(mi * mi + mj * mj + C1c);
    const float S2 = (2.f * cov + C2c) * __builtin_amdgcn_rcpf(vi + vj + C2c);
    sffr[r] = 1.f - S1 * S2;
  }

  // ---- Broadcast to wave-uniform SGPRs -----------------------------------
  int jjs[K], jis[K];
#pragma unroll
  for (int k = 0; k < K; ++k) {
    jjs[k] = __builtin_amdgcn_readlane(myidx, k);
    jis[k] = __builtin_amdgcn_readlane(myidx, 18 + k);
  }

  // ---- Phase 2: packed f16 xp accumulation -------------------------------
  const uint32* xpb32 = (const uint32*)(xpT + (size_t)b * N * C);
  const int l = (lane < 48) ? lane : 47;
  h2 accT[4] = {h2{0, 0}, h2{0, 0}, h2{0, 0}, h2{0, 0}};
  h2 accX[4] = {h2{0, 0}, h2{0, 0}, h2{0, 0}, h2{0, 0}};
#pragma unroll
  for (int k = 0; k < K; ++k) {
    const float sf = readlane_f(sffr[k >> 3], (k & 7) * 8);
    const _Float16 sh = (_Float16)sf;
    const h2 sf2 = h2{sh, sh};
    const h2 a = u2h2(xpb32[(size_t)jis[k] * 48 + l]);
    const h2 q = u2h2(xpb32[(size_t)jjs[k] * 48 + l]);
    accT[k & 3] = accT[k & 3] + (a + q);
    accX[k & 3] = habs2(a - q) * sf2 + accX[k & 3];
  }
  const float2 t0 = h22f2(accT[0]), t1 = h22f2(accT[1]);
  const float2 t2 = h22f2(accT[2]), t3 = h22f2(accT[3]);
  const float2 x0 = h22f2(accX[0]), x1 = h22f2(accX[1]);
  const float2 x2 = h22f2(accX[2]), x3 = h22f2(accX[3]);
  const float resx = (t0.x + t1.x) + (t2.x + t3.x) + (x0.x + x1.x) + (x2.x + x3.x);
  const float resy = (t0.y + t1.y) + (t2.y + t3.y) + (x0.y + x1.y) + (x2.y + x3.y);

  // ---- stage results in LDS, then block-coalesced store ------------------
  if (lane < 48) {
    ored[wave][2 * lane] = resx;
    ored[wave][2 * lane + 1] = resy;
  }
  __syncthreads();
  const int n0 = tile * 4;
  const int tid = threadIdx.x;
  {
    const int ch = tid >> 2, nn = tid & 3;  // ch 0..63
    out[((size_t)b * C + ch) * N + n0 + nn] = ored[nn][ch];
  }
  if (tid < 128) {
    const int t2i = 256 + tid;
    const int ch = t2i >> 2, nn = t2i & 3;  // ch 64..95
    out[((size_t)b * C + ch) * N + n0 + nn] = ored[nn][ch];
  }
}

// ---------------------------------------------------------------------------
// Fallback (only used if ws_size is too small): slow but correct (f32).
// ---------------------------------------------------------------------------
__global__ void fallback_kernel(const float* __restrict__ x,
                                const float* __restrict__ xp,
                                const int* __restrict__ e,
                                float* __restrict__ out) {
  const int gn = blockIdx.x * 64 + threadIdx.x;
  if (gn >= B * N) return;
  const int b = gn / N;
  const int n = gn - b * N;
  const float* xb = x + (size_t)b * C * N;
  const float* xpb = xp + (size_t)b * C * N;
  int ii[K], jj[K];
  float sff[K];
#pragma unroll
  for (int k = 0; k < K; ++k) {
    jj[k] = e[((size_t)(0 * B + b) * N + n) * K + k];
    ii[k] = e[((size_t)(1 * B + b) * N + n) * K + k];
    float si = 0, sj = 0, sii = 0, sjj = 0, sij = 0;
    for (int c = 0; c < C; ++c) {
      const float a = xb[(size_t)c * N + ii[k]];
      const float q = xb[(size_t)c * N + jj[k]];
      si += a; sj += q; sii += a * a; sjj += q * q; sij += a * q;
    }
    const float mi = si * (1.f / C), mj = sj * (1.f / C);
    const float vi = sii * (1.f / C) - mi * mi;
    const float vj = sjj * (1.f / C) - mj * mj;
    const float cov = sij * (1.f / C) - mi * mj;
    const float S1 = (2.f * mi * mj + C1c) / (mi * mi + mj * mj + C1c);
    const float S2 = (2.f * cov + C2c) / (vi + vj + C2c);
    sff[k] = 1.f - S1 * S2;
  }
  for (int c = 0; c < C; ++c) {
    float acc = 0.f;
#pragma unroll
    for (int k = 0; k < K; ++k) {
      const float a = xpb[(size_t)c * N + ii[k]];
      const float q = xpb[(size_t)c * N + jj[k]];
      acc += a + q + fabsf(a - q) * sff[k];
    }
    out[((size_t)b * C + c) * N + n] = acc;
  }
}

// ---------------------------------------------------------------------------
extern "C" void kernel_launch(void* const* d_in, const int* in_sizes, int n_in,
                              void* d_out, int out_size, void* d_ws, size_t ws_size,
                              hipStream_t stream) {
  const float* x = (const float*)d_in[0];
  const float* xp = (const float*)d_in[1];
  const int* e = (const int*)d_in[2];
  float* out = (float*)d_out;

  const size_t nBNC = (size_t)B * N * C;
  const size_t nBN = (size_t)B * N;
  const size_t need = 2 * nBNC * sizeof(ushort16) + nBN * sizeof(float2);

  if (ws_size >= need) {
    ushort16* xT = (ushort16*)d_ws;
    ushort16* xpT = xT + nBNC;
    float2* cstat = (float2*)(xpT + nBNC);

    fusedT_kernel<<<8 * (N / 32), 256, 0, stream>>>(x, xp, xT, xpT, cstat);
    ssim_main_kernel<<<(B * N) / 4, 256, 0, stream>>>(xT, xpT, cstat, e, out);
  } else {
    fallback_kernel<<<(B * N + 63) / 64, 64, 0, stream>>>(x, xp, e, out);
  }
}